// Round 10
// baseline (564.328 us; speedup 1.0000x reference)
//
#include <hip/hip_runtime.h>
#include <math.h>

#define LSEQ 1024
#define NB 64

typedef __attribute__((ext_vector_type(4))) float f32x4;
typedef __attribute__((ext_vector_type(8))) short bf16x8;
typedef __attribute__((ext_vector_type(4))) unsigned short u16x4;

__device__ __forceinline__ unsigned short f2bf(float x) {
    union { float f; unsigned int u; } a; a.f = x;
    unsigned int r = a.u + 0x7FFFu + ((a.u >> 16) & 1u);
    return (unsigned short)(r >> 16);
}
__device__ __forceinline__ float bf2f(unsigned short h) {
    union { float f; unsigned int u; } a; a.u = ((unsigned int)h) << 16;
    return a.f;
}
__device__ __forceinline__ float sigmoidf_(float x) { return 1.0f / (1.0f + __expf(-x)); }
__device__ __forceinline__ float seluf_(float x) {
    const float sc = 1.0507009873554805f, al = 1.6732632423543772f;
    return x > 0.0f ? sc * x : sc * al * (__expf(x) - 1.0f);
}
__device__ __forceinline__ void gload16(const unsigned short* g, unsigned short* l) {
    __builtin_amdgcn_global_load_lds(
        (const __attribute__((address_space(1))) unsigned int*)g,
        (__attribute__((address_space(3))) unsigned int*)l, 16, 0, 0);
}

// W (K x N fp32, N = 2*128*kw) -> Wt rows np = dir*128kw + hc*64kw + j*64 + (h&63), bf16 [np][k]
__global__ __launch_bounds__(256) void conv_wt(const float* __restrict__ W,
                                               unsigned short* __restrict__ Wt,
                                               int K, int N, int kw) {
    int idx = blockIdx.x * 256 + threadIdx.x;
    if (idx >= K * N) return;
    int k = idx / N, n = idx - k * N;
    const int dir = n / (128 * kw);
    const int rem = n - dir * 128 * kw;
    const int h = rem / kw, j = rem - h * kw;
    const int np = dir * 128 * kw + (h >> 6) * (64 * kw) + j * 64 + (h & 63);
    Wt[(size_t)np * K + k] = f2bf(W[idx]);
}

// input (L,B,128) fp32 -> inputT (B,L,128) bf16
__global__ __launch_bounds__(256) void conv_in_t(const float* __restrict__ in,
                                                 unsigned short* __restrict__ outp) {
    const int idx = blockIdx.x * 256 + threadIdx.x;  // (b, t, d4)
    const int d4 = idx & 31;
    const int t = (idx >> 5) & 1023;
    const int b = idx >> 15;
    const float4 v = *reinterpret_cast<const float4*>(&in[((size_t)t * NB + b) * 128 + d4 * 4]);
    u16x4 w;
    w[0] = f2bf(v.x); w[1] = f2bf(v.y); w[2] = f2bf(v.z); w[3] = f2bf(v.w);
    *(u16x4*)(&outp[((size_t)b * LSEQ + t) * 128 + d4 * 4]) = w;
}

// ---- fused SRU layer: GEMM (U in LDS only) + scan + output, one block per
// (b, dir, hc). X layout (B, L, D). 256 threads = 4 waves; per 32-t chunk:
//   GEMM: all waves, cols split by wave (v6-verified swapped-MFMA mapping)
//   S1: f=sig(u1+bf), g=(1-f)u0, r=sig(u2+br) in-place in LDS (parallel)
//   chain: wave0, c = fma(f,c,g) reg-resident, 32 steps (+LDS c stash)
//   S3: h = r*selu(c)+(1-r)*xp -> X write or feats accumulation (parallel)
template <int KW, int K, bool XP_FROM_U, bool ACC>
__global__ __launch_bounds__(256) void fused_layer(const unsigned short* __restrict__ A,
                                                   const unsigned short* __restrict__ Bt,
                                                   const float* __restrict__ bias,
                                                   unsigned short* __restrict__ Xout,
                                                   float* __restrict__ feats) {
    constexpr int WC = 64 * KW;   // block cols = KW planes x 64 channels
    constexpr int WCp = WC + 4;   // f32 row stride: keeps 16B align, spreads banks
    constexpr int NT = K / 64;
    constexpr int NF = KW;        // col-frags per wave (4 waves x NF*16 = WC)
    __shared__ __align__(16) unsigned short smB[WC * K];
    __shared__ __align__(16) float Ulds[32 * WCp];

    const int bid = blockIdx.x;
    const int b = bid >> 2, dir = (bid >> 1) & 1, hc = bid & 1;
    const int n0 = dir * (128 * KW) + hc * (64 * KW);

    const int tid = threadIdx.x;
    const int w = tid >> 6, l = tid & 63;
    const int rlo = l & 15, g = l >> 4;
    const int kswz = (rlo & 7) * 8;
    const int ch = tid & 63, tq = tid >> 6;

    const float bfb = bias[dir * 128 + hc * 64 + ch];
    const float brb = bias[256 + dir * 128 + hc * 64 + ch];

    // ---- B resident (once): pre-swizzled source, linear LDS dest ----
#pragma unroll
    for (int kt = 0; kt < NT; ++kt)
#pragma unroll
        for (int cc = 0; cc < WC / 32; ++cc) {
            const int col = cc * 32 + (tid >> 3);
            const int kxb = (tid & 7) ^ ((tid >> 3) & 7);
            gload16(Bt + (size_t)(n0 + col) * K + kt * 64 + kxb * 8,
                    &smB[kt * (WC * 64) + cc * 2048 + tid * 8]);
        }
    __syncthreads();

    float c = 0.0f;      // recurrence state (wave0 lanes = channels)
    float psum = 0.0f;   // time-sum for ACC (per (tq,ch) thread)

    for (int ci = 0; ci < 32; ++ci) {
        const int t0c = dir ? (LSEQ - 32 * (ci + 1)) : 32 * ci;
        const unsigned short* gA = A + ((size_t)b * LSEQ + t0c) * K;

        // ---- GEMM chunk: 32 rows x WC cols, wave w covers cols [w*NF*16, ...) ----
        {
            f32x4 acc[2][NF];
#pragma unroll
            for (int mf = 0; mf < 2; ++mf)
#pragma unroll
                for (int nf = 0; nf < NF; ++nf) acc[mf][nf] = (f32x4){0.f, 0.f, 0.f, 0.f};
#pragma unroll
            for (int kt = 0; kt < NT; ++kt) {
                bf16x8 af[2][2];
#pragma unroll
                for (int mf = 0; mf < 2; ++mf)
#pragma unroll
                    for (int kk = 0; kk < 2; ++kk)
                        af[mf][kk] = *(const bf16x8*)(gA + (size_t)(mf * 16 + rlo) * K +
                                                      kt * 64 + kk * 32 + g * 8);
#pragma unroll
                for (int kk = 0; kk < 2; ++kk) {
#pragma unroll
                    for (int nf = 0; nf < NF; ++nf) {
                        const int colf = (w * NF + nf) * 16 + rlo;
                        const int koff = (kk * 32 + g * 8) ^ kswz;
                        const bf16x8 bff =
                            *(const bf16x8*)(&smB[kt * (WC * 64) + colf * 64 + koff]);
#pragma unroll
                        for (int mf = 0; mf < 2; ++mf)
                            acc[mf][nf] = __builtin_amdgcn_mfma_f32_16x16x32_bf16(
                                bff, af[mf][kk], acc[mf][nf], 0, 0, 0);
                    }
                }
            }
            // store U chunk to LDS: lane holds rows mf*16+rlo, cols nf16 + g*4 + j
#pragma unroll
            for (int mf = 0; mf < 2; ++mf)
#pragma unroll
                for (int nf = 0; nf < NF; ++nf) {
                    const int lt = mf * 16 + rlo;
                    const int cf = (w * NF + nf) * 16 + g * 4;
                    *(f32x4*)(&Ulds[lt * WCp + cf]) = acc[mf][nf];
                }
        }
        __syncthreads();

        // ---- S1: gates (parallel). planes: 0=u0->g, 1=u1->f, 2=u2->r, 3=xp ----
#pragma unroll
        for (int ii = 0; ii < 8; ++ii) {
            const int lt = tq * 8 + ii;
            const float u0 = Ulds[lt * WCp + ch];
            const float u1 = Ulds[lt * WCp + 64 + ch];
            const float u2 = Ulds[lt * WCp + 128 + ch];
            const float f = sigmoidf_(u1 + bfb);
            const float r = sigmoidf_(u2 + brb);
            Ulds[lt * WCp + ch] = (1.0f - f) * u0;  // g
            Ulds[lt * WCp + 64 + ch] = f;
            Ulds[lt * WCp + 128 + ch] = r;
        }
        __syncthreads();

        // ---- chain: wave0, lane = channel; c over g-slot ----
        if (w == 0) {
            float fv[32], gv[32];
#pragma unroll
            for (int j = 0; j < 32; ++j) {
                fv[j] = Ulds[j * WCp + 64 + l];
                gv[j] = Ulds[j * WCp + l];
            }
            if (dir == 0) {
#pragma unroll
                for (int j = 0; j < 32; ++j) {
                    c = fmaf(fv[j], c, gv[j]);
                    Ulds[j * WCp + l] = c;
                }
            } else {
#pragma unroll
                for (int j = 31; j >= 0; --j) {
                    c = fmaf(fv[j], c, gv[j]);
                    Ulds[j * WCp + l] = c;
                }
            }
        }
        __syncthreads();

        // ---- S3: outputs (parallel) ----
#pragma unroll
        for (int ii = 0; ii < 8; ++ii) {
            const int lt = tq * 8 + ii;
            const int t = t0c + lt;
            const float cv = Ulds[lt * WCp + ch];
            const float r = Ulds[lt * WCp + 128 + ch];
            float xp;
            if constexpr (XP_FROM_U)
                xp = Ulds[lt * WCp + 192 + ch];
            else
                xp = bf2f(A[((size_t)b * LSEQ + t) * K + dir * 128 + hc * 64 + ch]);
            const float ho = r * seluf_(cv) + (1.0f - r) * xp;
            if constexpr (ACC)
                psum += ho;
            else
                Xout[((size_t)b * LSEQ + t) * 256 + dir * 128 + hc * 64 + ch] = f2bf(ho);
        }
        __syncthreads();  // Ulds free for next chunk's GEMM
    }

    if constexpr (ACC) {
        Ulds[tq * 64 + ch] = psum;
        __syncthreads();
        if (tid < 64) {
            const float s = Ulds[tid] + Ulds[64 + tid] + Ulds[128 + tid] + Ulds[192 + tid];
            feats[b * 256 + dir * 128 + hc * 64 + tid] = s * (1.0f / (float)LSEQ);
        }
    }
}

// layernorm over feats (B x 256 fp32)
__global__ __launch_bounds__(256) void ln_out(const float* __restrict__ feats,
                                              const float* __restrict__ gamma,
                                              const float* __restrict__ beta,
                                              float* __restrict__ out) {
    const int b = blockIdx.x, chn = threadIdx.x;
    const float feat = feats[b * 256 + chn];
    __shared__ float red[256];
    red[chn] = feat; __syncthreads();
    for (int off = 128; off > 0; off >>= 1) { if (chn < off) red[chn] += red[chn + off]; __syncthreads(); }
    const float mu = red[0] * (1.0f / 256.0f);
    __syncthreads();
    const float d = feat - mu;
    red[chn] = d * d; __syncthreads();
    for (int off = 128; off > 0; off >>= 1) { if (chn < off) red[chn] += red[chn + off]; __syncthreads(); }
    const float var = red[0] * (1.0f / 256.0f);
    out[b * 256 + chn] = d * rsqrtf(var + 1e-5f) * gamma[chn] + beta[chn];
}

extern "C" void kernel_launch(void* const* d_in, const int* in_sizes, int n_in,
                              void* d_out, int out_size, void* d_ws, size_t ws_size,
                              hipStream_t stream) {
    const float* input = (const float*)d_in[0];
    const float* gamma = (const float*)d_in[3];
    const float* beta  = (const float*)d_in[4];
    const float* Wl[4] = { (const float*)d_in[1], (const float*)d_in[5],
                           (const float*)d_in[7], (const float*)d_in[9] };
    const float* bl[4] = { (const float*)d_in[2], (const float*)d_in[6],
                           (const float*)d_in[8], (const float*)d_in[10] };
    float* out = (float*)d_out;

    char* base = (char*)d_ws;
    size_t off = 0;
    auto alloc = [&](size_t bytes) { size_t o = off; off = (off + bytes + 255) & ~(size_t)255; return o; };

    unsigned short* Wt[4];
    Wt[0] = (unsigned short*)(base + alloc((size_t)1024 * 128 * 2));
    for (int i = 1; i < 4; ++i) Wt[i] = (unsigned short*)(base + alloc((size_t)768 * 256 * 2));
    unsigned short* Xc = (unsigned short*)(base + alloc((size_t)NB * LSEQ * 128 * 2));  // inputT
    unsigned short* Xa = (unsigned short*)(base + alloc((size_t)NB * LSEQ * 256 * 2));
    unsigned short* Xb = (unsigned short*)(base + alloc((size_t)NB * LSEQ * 256 * 2));
    float* feats = (float*)(base + alloc((size_t)NB * 256 * 4));
    if (ws_size < off) return;

    conv_in_t<<<dim3(NB * LSEQ * 32 / 256), 256, 0, stream>>>(input, Xc);
    conv_wt<<<dim3((128 * 1024 + 255) / 256), 256, 0, stream>>>(Wl[0], Wt[0], 128, 1024, 4);
    for (int i = 1; i < 4; ++i)
        conv_wt<<<dim3((256 * 768 + 255) / 256), 256, 0, stream>>>(Wl[i], Wt[i], 256, 768, 3);

    fused_layer<4, 128, true, false><<<dim3(256), 256, 0, stream>>>(Xc, Wt[0], bl[0], Xa, nullptr);
    fused_layer<3, 256, false, false><<<dim3(256), 256, 0, stream>>>(Xa, Wt[1], bl[1], Xb, nullptr);
    fused_layer<3, 256, false, false><<<dim3(256), 256, 0, stream>>>(Xb, Wt[2], bl[2], Xa, nullptr);
    fused_layer<3, 256, false, true><<<dim3(256), 256, 0, stream>>>(Xa, Wt[3], bl[3], nullptr, feats);

    ln_out<<<dim3(NB), 256, 0, stream>>>(feats, gamma, beta, out);
}